// Round 8
// baseline (167.007 us; speedup 1.0000x reference)
//
#include <hip/hip_runtime.h>
#include <hip/hip_bf16.h>
#include <math.h>

#define NN 4096      // nodes
#define C  256       // feature dim
#define NH 8         // heads
#define HD 32        // head dim
#define LN_EPS 1e-5f
#define LOG2E 1.44269504088896340736f

typedef unsigned short u16;
typedef __attribute__((ext_vector_type(8))) short bf16x8;
typedef __attribute__((ext_vector_type(4))) float f32x4;

__device__ inline u16 f2b(float f) {
    union { float f; unsigned u; } v; v.f = f;
    unsigned r = (v.u + 0x7fff + ((v.u >> 16) & 1)) >> 16;  // RNE
    return (u16)r;
}

__device__ inline float fexp2(float x) {
#if __has_builtin(__builtin_amdgcn_exp2f)
    return __builtin_amdgcn_exp2f(x);      // single v_exp_f32
#else
    return exp2f(x);
#endif
}

// pack bf16(e0)|bf16(e1)<<16 by truncation: ONE v_perm_b32
__device__ inline unsigned pack_trunc(float e0, float e1) {
    return __builtin_amdgcn_perm(__float_as_uint(e1), __float_as_uint(e0),
                                 0x07060302u);
}

__device__ inline void atomic_add_agent(float* p, float v) {
    __hip_atomic_fetch_add(p, v, __ATOMIC_RELAXED, __HIP_MEMORY_SCOPE_AGENT);
}

// ---------------------------------------------------------------------------
// Kernel 0: prep — z<4: weight transpose+bf16; z=4..7: x fp32->bf16;
// z=8..11: zero msgacc+lacc (replaces the hipMemsetAsync dispatch).
// grid (8,8,12), block 256.
// ---------------------------------------------------------------------------
#define ZERO_FLOATS ((size_t)NN * C + (size_t)NN * NH)
__global__ __launch_bounds__(256) void prep_kernel(
    const float* __restrict__ Wq, const float* __restrict__ Wk,
    const float* __restrict__ Wv, const float* __restrict__ Wo,
    const float* __restrict__ x,
    u16* __restrict__ WqkvT, u16* __restrict__ WoT, u16* __restrict__ xb,
    float* __restrict__ zacc)
{
    const int z = blockIdx.z;
    if (z < 4) {
        __shared__ float tile[32][33];
        const float* W = (z == 0) ? Wq : (z == 1) ? Wk : (z == 2) ? Wv : Wo;
        u16* WT = (z == 3) ? WoT : (WqkvT + (size_t)z * 256 * 256);
        const int tx = threadIdx.x & 31, ty = threadIdx.x >> 5;
        const int n0 = blockIdx.x * 32, k0 = blockIdx.y * 32;
        #pragma unroll
        for (int i = 0; i < 32; i += 8)
            tile[ty + i][tx] = W[(size_t)(k0 + ty + i) * 256 + n0 + tx];
        __syncthreads();
        #pragma unroll
        for (int i = 0; i < 32; i += 8)
            WT[(size_t)(n0 + ty + i) * 256 + k0 + tx] = f2b(tile[tx][ty + i]);
    } else if (z < 8) {
        // x conversion: 4 slices x 64 blocks x 256 thr x 16 elems = NN*C
        const int slice = z - 4;
        const int bid = blockIdx.x * 8 + blockIdx.y;
        const int base = slice * (NN * C / 4) + bid * 4096 + threadIdx.x * 16;
        #pragma unroll
        for (int i = 0; i < 4; ++i) {
            const float4 v = *(const float4*)(x + base + i * 4);
            union { u16 u[4]; unsigned long long ull; } pk;
            pk.u[0] = f2b(v.x); pk.u[1] = f2b(v.y);
            pk.u[2] = f2b(v.z); pk.u[3] = f2b(v.w);
            *(unsigned long long*)(xb + base + i * 4) = pk.ull;
        }
    } else {
        // zero msgacc+lacc: 4 slices x 64 blocks x 256 thr, grid-stride float4
        const int gid = ((z - 8) * 64 + blockIdx.x * 8 + blockIdx.y) * 256
                        + threadIdx.x;
        const float4 zf = {0.f, 0.f, 0.f, 0.f};
        for (size_t i = (size_t)gid * 4; i < ZERO_FLOATS; i += (size_t)65536 * 4)
            *(float4*)(zacc + i) = zf;
    }
}

// ---------------------------------------------------------------------------
// Kernel 1: QKV projection via MFMA (64x64 tiles, 4 waves). A-frag is a
// single 16B load from pre-converted xb. qb pre-scaled by scale*log2e;
// v emitted as V^T.
// ---------------------------------------------------------------------------
__global__ __launch_bounds__(256) void qkv_mfma_kernel(
    const u16* __restrict__ xb, const u16* __restrict__ WT,
    const float* __restrict__ bq, const float* __restrict__ bk,
    const float* __restrict__ bv, const float* __restrict__ scale_p,
    u16* __restrict__ qb, u16* __restrict__ kb, u16* __restrict__ vT)
{
    const int m0 = blockIdx.x * 64;
    const int n0 = blockIdx.y * 64;
    const int t = threadIdx.x;
    const int wave = t >> 6, lane = t & 63;
    const int l16 = lane & 15, quad = lane >> 4;

    f32x4 acc[4];
    #pragma unroll
    for (int ct = 0; ct < 4; ++ct) acc[ct] = f32x4{0.f, 0.f, 0.f, 0.f};

    const u16* xrow = xb + (size_t)(m0 + wave * 16 + l16) * C;
    #pragma unroll
    for (int kk = 0; kk < 8; ++kk) {
        const bf16x8 af = *(const bf16x8*)(xrow + kk * 32 + quad * 8);
        #pragma unroll
        for (int ct = 0; ct < 4; ++ct) {
            const bf16x8 bfr = *(const bf16x8*)(
                WT + (size_t)(n0 + ct * 16 + l16) * C + kk * 32 + quad * 8);
            acc[ct] = __builtin_amdgcn_mfma_f32_16x16x32_bf16(af, bfr, acc[ct], 0, 0, 0);
        }
    }

    const int sect = n0 >> 8;
    const int c0 = n0 & 255;
    const int rbase = m0 + wave * 16 + quad * 4;
    if (sect == 0) {
        const float scl = (*scale_p) * LOG2E;
        #pragma unroll
        for (int ct = 0; ct < 4; ++ct) {
            const int c = c0 + ct * 16 + l16;
            const float b = bq[c];
            #pragma unroll
            for (int r = 0; r < 4; ++r)
                qb[(size_t)(rbase + r) * C + c] = f2b((acc[ct][r] + b) * scl);
        }
    } else if (sect == 1) {
        #pragma unroll
        for (int ct = 0; ct < 4; ++ct) {
            const int c = c0 + ct * 16 + l16;
            const float b = bk[c];
            #pragma unroll
            for (int r = 0; r < 4; ++r)
                kb[(size_t)(rbase + r) * C + c] = f2b(acc[ct][r] + b);
        }
    } else {
        #pragma unroll
        for (int ct = 0; ct < 4; ++ct) {
            const int c = c0 + ct * 16 + l16;
            const float b = bv[c];
            union { u16 u[4]; unsigned long long ull; } pk;
            #pragma unroll
            for (int r = 0; r < 4; ++r) pk.u[r] = f2b(acc[ct][r] + b);
            *(unsigned long long*)(vT + (size_t)c * NN + rbase) = pk.ull;
        }
    }
}

// ---------------------------------------------------------------------------
// Kernel 2: MFMA attention, S^T formulation, no max-shift, key-split NZ-way
// (NZ=8 for full occupancy: 4096 blocks, LDS 18.9KB -> 8 blocks/CU).
// ---------------------------------------------------------------------------
#define TQ 64
#define TJ 64
#define NZ 8
#define ZT (NN / NZ)
#define KSTRIDE 40
#define VSTRIDE 72

__global__ __launch_bounds__(256) void attn_mfma_kernel(
    const u16* __restrict__ q, const u16* __restrict__ k,
    const u16* __restrict__ vT, float* __restrict__ msgacc,
    float* __restrict__ lacc)
{
    __shared__ u16 Ks[TJ * KSTRIDE];
    __shared__ u16 Vs[HD * VSTRIDE];
    __shared__ u16 Ps[4][16 * VSTRIDE];

    const int qbase = blockIdx.x * TQ;
    const int h = blockIdx.y;
    const int z = blockIdx.z;
    const int t = threadIdx.x;
    const int wave = t >> 6;
    const int lane = t & 63;
    const int l16 = lane & 15;
    const int quad = lane >> 4;

    const bf16x8 qfrag = *(const bf16x8*)(
        q + (size_t)(qbase + wave * 16 + l16) * C + h * HD + quad * 8);

    float lsum = 0.f;
    f32x4 o0 = {0.f, 0.f, 0.f, 0.f};
    f32x4 o1 = {0.f, 0.f, 0.f, 0.f};

    const int sj = t >> 2, sc = t & 3;
    const int sd = t >> 3, se = t & 7;

    for (int j0 = z * ZT; j0 < z * ZT + ZT; j0 += TJ) {
        __syncthreads();
        *(bf16x8*)(Ks + sj * KSTRIDE + sc * 8) =
            *(const bf16x8*)(k + (size_t)(j0 + sj) * C + h * HD + sc * 8);
        *(bf16x8*)(Vs + sd * VSTRIDE + se * 8) =
            *(const bf16x8*)(vT + (size_t)(h * HD + sd) * NN + j0 + se * 8);
        __syncthreads();

        f32x4 st[4];
        #pragma unroll
        for (int ct = 0; ct < 4; ++ct) {
            const bf16x8 kf = *(const bf16x8*)(Ks + (ct * 16 + l16) * KSTRIDE + quad * 8);
            f32x4 zz = {0.f, 0.f, 0.f, 0.f};
            st[ct] = __builtin_amdgcn_mfma_f32_16x16x32_bf16(kf, qfrag, zz, 0, 0, 0);
        }

        #pragma unroll
        for (int ct = 0; ct < 4; ++ct) {
            const float e0 = fexp2(st[ct][0]);
            const float e1 = fexp2(st[ct][1]);
            const float e2 = fexp2(st[ct][2]);
            const float e3 = fexp2(st[ct][3]);
            lsum += (e0 + e1) + (e2 + e3);
            const unsigned lo = pack_trunc(e0, e1);
            const unsigned hi = pack_trunc(e2, e3);
            *(unsigned long long*)(&Ps[wave][l16 * VSTRIDE + ct * 16 + quad * 4]) =
                (unsigned long long)lo | ((unsigned long long)hi << 32);
        }

        asm volatile("s_waitcnt lgkmcnt(0)" ::: "memory");  // wave-private Ps

        #pragma unroll
        for (int ks = 0; ks < 2; ++ks) {
            const bf16x8 pf = *(const bf16x8*)(&Ps[wave][l16 * VSTRIDE + ks * 32 + quad * 8]);
            const bf16x8 vf0 = *(const bf16x8*)(Vs + l16 * VSTRIDE + ks * 32 + quad * 8);
            const bf16x8 vf1 = *(const bf16x8*)(Vs + (16 + l16) * VSTRIDE + ks * 32 + quad * 8);
            o0 = __builtin_amdgcn_mfma_f32_16x16x32_bf16(pf, vf0, o0, 0, 0, 0);
            o1 = __builtin_amdgcn_mfma_f32_16x16x32_bf16(pf, vf1, o1, 0, 0, 0);
        }
    }

    lsum += __shfl_xor(lsum, 16);
    lsum += __shfl_xor(lsum, 32);
    if (quad == 0)
        atomic_add_agent(&lacc[(size_t)(qbase + wave * 16 + l16) * NH + h], lsum);

    #pragma unroll
    for (int r = 0; r < 4; ++r) {
        const int row = qbase + wave * 16 + quad * 4 + r;
        atomic_add_agent(&msgacc[(size_t)row * C + h * HD + l16], o0[r]);
        atomic_add_agent(&msgacc[(size_t)row * C + h * HD + 16 + l16], o1[r]);
    }
}

// ---------------------------------------------------------------------------
// Kernel 3: y = x + (msgacc/l) @ Wo + bo, LayerNorm. 4-row tiles -> 1024
// blocks (4/CU). MFMA computes 16 rows; rows 4..15 discarded (quad 0 only
// in epilogue). A-frag rows folded to m0..m0+3 via (l16 & 3).
// ---------------------------------------------------------------------------
#define OROWS 4
__global__ __launch_bounds__(256) void out_ln_mfma_kernel(
    const float* __restrict__ msgacc, const float* __restrict__ lacc,
    const u16* __restrict__ WoT, const float* __restrict__ bo,
    const float* __restrict__ x, const float* __restrict__ gamma,
    const float* __restrict__ beta, float* __restrict__ out)
{
    __shared__ float sums[2][4][OROWS];
    const int m0 = blockIdx.x * OROWS;
    const int t = threadIdx.x;
    const int w = t >> 6, lane = t & 63;
    const int l16 = lane & 15, quad = lane >> 4;

    f32x4 acc[4];
    #pragma unroll
    for (int ct = 0; ct < 4; ++ct) acc[ct] = f32x4{0.f, 0.f, 0.f, 0.f};

    const int ar = m0 + (l16 & 3);   // rows 4..15 of D are discarded
    const float* arow = msgacc + (size_t)ar * C;
    const float* lrow = lacc + (size_t)ar * NH;
    #pragma unroll
    for (int kk = 0; kk < 8; ++kk) {
        const float li = 1.f / lrow[kk];
        const float4 a0 = *(const float4*)(arow + kk * 32 + quad * 8);
        const float4 a1 = *(const float4*)(arow + kk * 32 + quad * 8 + 4);
        union { __hip_bfloat162 h2[4]; bf16x8 v; } af;
        af.h2[0] = __float22bfloat162_rn(float2{a0.x * li, a0.y * li});
        af.h2[1] = __float22bfloat162_rn(float2{a0.z * li, a0.w * li});
        af.h2[2] = __float22bfloat162_rn(float2{a1.x * li, a1.y * li});
        af.h2[3] = __float22bfloat162_rn(float2{a1.z * li, a1.w * li});
        #pragma unroll
        for (int ct = 0; ct < 4; ++ct) {
            const bf16x8 bfr = *(const bf16x8*)(
                WoT + (size_t)(w * 64 + ct * 16 + l16) * C + kk * 32 + quad * 8);
            acc[ct] = __builtin_amdgcn_mfma_f32_16x16x32_bf16(af.v, bfr, acc[ct], 0, 0, 0);
        }
    }

    float val[4][4];
    if (quad == 0) {
        #pragma unroll
        for (int r = 0; r < 4; ++r) {
            const int row = m0 + r;
            float sr = 0.f, qr = 0.f;
            #pragma unroll
            for (int ct = 0; ct < 4; ++ct) {
                const int c = w * 64 + ct * 16 + l16;
                const float v = acc[ct][r] + bo[c] + x[(size_t)row * C + c];
                val[ct][r] = v;
                sr += v;
                qr = fmaf(v, v, qr);
            }
            sr += __shfl_xor(sr, 1); sr += __shfl_xor(sr, 2);
            sr += __shfl_xor(sr, 4); sr += __shfl_xor(sr, 8);
            qr += __shfl_xor(qr, 1); qr += __shfl_xor(qr, 2);
            qr += __shfl_xor(qr, 4); qr += __shfl_xor(qr, 8);
            if (l16 == 0) {
                sums[0][w][r] = sr;
                sums[1][w][r] = qr;
            }
        }
    }
    __syncthreads();

    if (quad == 0) {
        #pragma unroll
        for (int r = 0; r < 4; ++r) {
            const int row = m0 + r;
            const float tot  = sums[0][0][r] + sums[0][1][r] + sums[0][2][r] + sums[0][3][r];
            const float tot2 = sums[1][0][r] + sums[1][1][r] + sums[1][2][r] + sums[1][3][r];
            const float mu = tot * (1.f / C);
            const float var = fmaxf(tot2 * (1.f / C) - mu * mu, 0.f);
            const float rstd = rsqrtf(var + LN_EPS);
            #pragma unroll
            for (int ct = 0; ct < 4; ++ct) {
                const int c = w * 64 + ct * 16 + l16;
                out[(size_t)row * C + c] = (val[ct][r] - mu) * rstd * gamma[c] + beta[c];
            }
        }
    }
}

// ---------------------------------------------------------------------------
extern "C" void kernel_launch(void* const* d_in, const int* in_sizes, int n_in,
                              void* d_out, int out_size, void* d_ws, size_t ws_size,
                              hipStream_t stream) {
    const float* x     = (const float*)d_in[0];
    const float* Wq    = (const float*)d_in[1];
    const float* bq    = (const float*)d_in[2];
    const float* Wk    = (const float*)d_in[3];
    const float* bk    = (const float*)d_in[4];
    const float* Wv    = (const float*)d_in[5];
    const float* bv    = (const float*)d_in[6];
    const float* scale = (const float*)d_in[7];
    const float* Wo    = (const float*)d_in[8];
    const float* bo    = (const float*)d_in[9];
    const float* gamma = (const float*)d_in[10];
    const float* beta  = (const float*)d_in[11];
    float* out = (float*)d_out;

    u16* qb     = (u16*)d_ws;                              // 2 MB
    u16* kb     = qb + (size_t)NN * C;                     // 2 MB
    u16* vT     = kb + (size_t)NN * C;                     // 2 MB
    u16* xbuf   = vT + (size_t)NN * C;                     // 2 MB
    u16* WqkvT  = xbuf + (size_t)NN * C;                   // 384 KB
    u16* WoT    = WqkvT + (size_t)3 * C * C;               // 128 KB
    float* msgacc = (float*)(WoT + (size_t)C * C);         // 4 MB
    float* lacc   = msgacc + (size_t)NN * C;               // 128 KB (contiguous)

    prep_kernel<<<dim3(8, 8, 12), 256, 0, stream>>>(Wq, Wk, Wv, Wo, x,
                                                    WqkvT, WoT, xbuf, msgacc);
    qkv_mfma_kernel<<<dim3(NN / 64, 12), 256, 0, stream>>>(
        xbuf, WqkvT, bq, bk, bv, scale, qb, kb, vT);
    attn_mfma_kernel<<<dim3(NN / TQ, NH, NZ), 256, 0, stream>>>(
        qb, kb, vT, msgacc, lacc);
    out_ln_mfma_kernel<<<NN / OROWS, 256, 0, stream>>>(msgacc, lacc, WoT, bo, x,
                                                       gamma, beta, out);
}

// Round 9
// 157.988 us; speedup vs baseline: 1.0571x; 1.0571x over previous
//
#include <hip/hip_runtime.h>
#include <hip/hip_bf16.h>
#include <math.h>

#define NN 4096      // nodes
#define C  256       // feature dim
#define NH 8         // heads
#define HD 32        // head dim
#define LN_EPS 1e-5f
#define LOG2E 1.44269504088896340736f

typedef unsigned short u16;
typedef __attribute__((ext_vector_type(8))) short bf16x8;
typedef __attribute__((ext_vector_type(4))) float f32x4;

__device__ inline u16 f2b(float f) {
    union { float f; unsigned u; } v; v.f = f;
    unsigned r = (v.u + 0x7fff + ((v.u >> 16) & 1)) >> 16;  // RNE
    return (u16)r;
}

__device__ inline float fexp2(float x) {
#if __has_builtin(__builtin_amdgcn_exp2f)
    return __builtin_amdgcn_exp2f(x);      // single v_exp_f32
#else
    return exp2f(x);
#endif
}

// pack bf16(e0) | bf16(e1)<<16 by truncation: ONE v_perm_b32
__device__ inline unsigned pack_trunc(float e0, float e1) {
    return __builtin_amdgcn_perm(__float_as_uint(e1), __float_as_uint(e0),
                                 0x07060302u);
}

__device__ inline void atomic_add_agent(float* p, float v) {
    __hip_atomic_fetch_add(p, v, __ATOMIC_RELAXED, __HIP_MEMORY_SCOPE_AGENT);
}

// ---------------------------------------------------------------------------
// Kernel 0: prep — z<4: weight transpose+bf16 (WqkvT=[Wq^T|Wk^T|Wv^T], WoT);
// z=4..7: x fp32->bf16. grid (8,8,8), block 256.  (R7 config)
// ---------------------------------------------------------------------------
__global__ __launch_bounds__(256) void prep_kernel(
    const float* __restrict__ Wq, const float* __restrict__ Wk,
    const float* __restrict__ Wv, const float* __restrict__ Wo,
    const float* __restrict__ x,
    u16* __restrict__ WqkvT, u16* __restrict__ WoT, u16* __restrict__ xb)
{
    const int z = blockIdx.z;
    if (z < 4) {
        __shared__ float tile[32][33];
        const float* W = (z == 0) ? Wq : (z == 1) ? Wk : (z == 2) ? Wv : Wo;
        u16* WT = (z == 3) ? WoT : (WqkvT + (size_t)z * 256 * 256);
        const int tx = threadIdx.x & 31, ty = threadIdx.x >> 5;
        const int n0 = blockIdx.x * 32, k0 = blockIdx.y * 32;
        #pragma unroll
        for (int i = 0; i < 32; i += 8)
            tile[ty + i][tx] = W[(size_t)(k0 + ty + i) * 256 + n0 + tx];
        __syncthreads();
        #pragma unroll
        for (int i = 0; i < 32; i += 8)
            WT[(size_t)(n0 + ty + i) * 256 + k0 + tx] = f2b(tile[tx][ty + i]);
    } else {
        // x conversion: 4 slices x 64 blocks x 256 thr x 16 elems = NN*C
        const int slice = z - 4;
        const int bid = blockIdx.x * 8 + blockIdx.y;
        const int base = slice * (NN * C / 4) + bid * 4096 + threadIdx.x * 16;
        #pragma unroll
        for (int i = 0; i < 4; ++i) {
            const float4 v = *(const float4*)(x + base + i * 4);
            union { u16 u[4]; unsigned long long ull; } pk;
            pk.u[0] = f2b(v.x); pk.u[1] = f2b(v.y);
            pk.u[2] = f2b(v.z); pk.u[3] = f2b(v.w);
            *(unsigned long long*)(xb + base + i * 4) = pk.ull;
        }
    }
}

// ---------------------------------------------------------------------------
// Kernel 1: QKV projection via MFMA (64x64 tiles, 4 waves). A-frag is a
// single 16B load from pre-converted xb. q/k epilogue now goes through an
// LDS transpose stage -> 2 coalesced b128 stores/thread (was 16 scattered
// 2B stores). v emitted as packed V^T (b64 column stores, unchanged).
// ---------------------------------------------------------------------------
#define TRS 80   // LDS transpose row stride in u16 (160B: 16B-aligned rows)
__global__ __launch_bounds__(256) void qkv_mfma_kernel(
    const u16* __restrict__ xb, const u16* __restrict__ WT,
    const float* __restrict__ bq, const float* __restrict__ bk,
    const float* __restrict__ bv, const float* __restrict__ scale_p,
    u16* __restrict__ qb, u16* __restrict__ kb, u16* __restrict__ vT)
{
    __shared__ u16 tr[64 * TRS];
    const int m0 = blockIdx.x * 64;
    const int n0 = blockIdx.y * 64;
    const int t = threadIdx.x;
    const int wave = t >> 6, lane = t & 63;
    const int l16 = lane & 15, quad = lane >> 4;

    f32x4 acc[4];
    #pragma unroll
    for (int ct = 0; ct < 4; ++ct) acc[ct] = f32x4{0.f, 0.f, 0.f, 0.f};

    const u16* xrow = xb + (size_t)(m0 + wave * 16 + l16) * C;
    #pragma unroll
    for (int kk = 0; kk < 8; ++kk) {
        const bf16x8 af = *(const bf16x8*)(xrow + kk * 32 + quad * 8);
        #pragma unroll
        for (int ct = 0; ct < 4; ++ct) {
            const bf16x8 bfr = *(const bf16x8*)(
                WT + (size_t)(n0 + ct * 16 + l16) * C + kk * 32 + quad * 8);
            acc[ct] = __builtin_amdgcn_mfma_f32_16x16x32_bf16(af, bfr, acc[ct], 0, 0, 0);
        }
    }

    const int sect = n0 >> 8;                // block-uniform
    const int c0 = n0 & 255;
    const int rloc = wave * 16 + quad * 4;   // local row base in the 64-tile
    if (sect == 2) {
        #pragma unroll
        for (int ct = 0; ct < 4; ++ct) {
            const int c = c0 + ct * 16 + l16;
            const float b = bv[c];
            union { u16 u[4]; unsigned long long ull; } pk;
            #pragma unroll
            for (int r = 0; r < 4; ++r) pk.u[r] = f2b(acc[ct][r] + b);
            *(unsigned long long*)(vT + (size_t)c * NN + m0 + rloc) = pk.ull;
        }
    } else {
        const float scl = (sect == 0) ? (*scale_p) * LOG2E : 1.f;
        const float* bias = (sect == 0) ? bq : bk;
        #pragma unroll
        for (int ct = 0; ct < 4; ++ct) {
            const float b = bias[c0 + ct * 16 + l16];
            #pragma unroll
            for (int r = 0; r < 4; ++r)
                tr[(rloc + r) * TRS + ct * 16 + l16] = f2b((acc[ct][r] + b) * scl);
        }
        __syncthreads();
        const int row = t >> 2, chunk = t & 3;
        u16* dst = ((sect == 0) ? qb : kb)
                   + (size_t)(m0 + row) * C + c0 + chunk * 16;
        const u16* src = tr + row * TRS + chunk * 16;
        *(bf16x8*)(dst)     = *(const bf16x8*)(src);
        *(bf16x8*)(dst + 8) = *(const bf16x8*)(src + 8);
    }
}

// ---------------------------------------------------------------------------
// Kernel 2: MFMA attention, S^T formulation, no max-shift, key-split NZ=4
// (R7 config — NZ=8 doubled atomic HBM writes and regressed).
// ---------------------------------------------------------------------------
#define TQ 64
#define TJ 64
#define NZ 4
#define ZT (NN / NZ)
#define KSTRIDE 40
#define VSTRIDE 72

__global__ __launch_bounds__(256) void attn_mfma_kernel(
    const u16* __restrict__ q, const u16* __restrict__ k,
    const u16* __restrict__ vT, float* __restrict__ msgacc,
    float* __restrict__ lacc)
{
    __shared__ u16 Ks[TJ * KSTRIDE];
    __shared__ u16 Vs[HD * VSTRIDE];
    __shared__ u16 Ps[4][16 * VSTRIDE];

    const int qbase = blockIdx.x * TQ;
    const int h = blockIdx.y;
    const int z = blockIdx.z;
    const int t = threadIdx.x;
    const int wave = t >> 6;
    const int lane = t & 63;
    const int l16 = lane & 15;
    const int quad = lane >> 4;

    const bf16x8 qfrag = *(const bf16x8*)(
        q + (size_t)(qbase + wave * 16 + l16) * C + h * HD + quad * 8);

    float lsum = 0.f;
    f32x4 o0 = {0.f, 0.f, 0.f, 0.f};
    f32x4 o1 = {0.f, 0.f, 0.f, 0.f};

    const int sj = t >> 2, sc = t & 3;
    const int sd = t >> 3, se = t & 7;

    for (int j0 = z * ZT; j0 < z * ZT + ZT; j0 += TJ) {
        __syncthreads();
        *(bf16x8*)(Ks + sj * KSTRIDE + sc * 8) =
            *(const bf16x8*)(k + (size_t)(j0 + sj) * C + h * HD + sc * 8);
        *(bf16x8*)(Vs + sd * VSTRIDE + se * 8) =
            *(const bf16x8*)(vT + (size_t)(h * HD + sd) * NN + j0 + se * 8);
        __syncthreads();

        f32x4 st[4];
        #pragma unroll
        for (int ct = 0; ct < 4; ++ct) {
            const bf16x8 kf = *(const bf16x8*)(Ks + (ct * 16 + l16) * KSTRIDE + quad * 8);
            f32x4 zz = {0.f, 0.f, 0.f, 0.f};
            st[ct] = __builtin_amdgcn_mfma_f32_16x16x32_bf16(kf, qfrag, zz, 0, 0, 0);
        }

        #pragma unroll
        for (int ct = 0; ct < 4; ++ct) {
            const float e0 = fexp2(st[ct][0]);
            const float e1 = fexp2(st[ct][1]);
            const float e2 = fexp2(st[ct][2]);
            const float e3 = fexp2(st[ct][3]);
            lsum += (e0 + e1) + (e2 + e3);
            const unsigned lo = pack_trunc(e0, e1);
            const unsigned hi = pack_trunc(e2, e3);
            *(unsigned long long*)(&Ps[wave][l16 * VSTRIDE + ct * 16 + quad * 4]) =
                (unsigned long long)lo | ((unsigned long long)hi << 32);
        }

        asm volatile("s_waitcnt lgkmcnt(0)" ::: "memory");  // wave-private Ps

        #pragma unroll
        for (int ks = 0; ks < 2; ++ks) {
            const bf16x8 pf = *(const bf16x8*)(&Ps[wave][l16 * VSTRIDE + ks * 32 + quad * 8]);
            const bf16x8 vf0 = *(const bf16x8*)(Vs + l16 * VSTRIDE + ks * 32 + quad * 8);
            const bf16x8 vf1 = *(const bf16x8*)(Vs + (16 + l16) * VSTRIDE + ks * 32 + quad * 8);
            o0 = __builtin_amdgcn_mfma_f32_16x16x32_bf16(pf, vf0, o0, 0, 0, 0);
            o1 = __builtin_amdgcn_mfma_f32_16x16x32_bf16(pf, vf1, o1, 0, 0, 0);
        }
    }

    lsum += __shfl_xor(lsum, 16);
    lsum += __shfl_xor(lsum, 32);
    if (quad == 0)
        atomic_add_agent(&lacc[(size_t)(qbase + wave * 16 + l16) * NH + h], lsum);

    #pragma unroll
    for (int r = 0; r < 4; ++r) {
        const int row = qbase + wave * 16 + quad * 4 + r;
        atomic_add_agent(&msgacc[(size_t)row * C + h * HD + l16], o0[r]);
        atomic_add_agent(&msgacc[(size_t)row * C + h * HD + 16 + l16], o1[r]);
    }
}

// ---------------------------------------------------------------------------
// Kernel 3: y = x + (msgacc/l) @ Wo + bo, LayerNorm. 8-row tiles, 512 blocks
// (R7 config). A-build uses single-instr v_perm truncation packs.
// ---------------------------------------------------------------------------
#define OROWS 8
__global__ __launch_bounds__(256) void out_ln_mfma_kernel(
    const float* __restrict__ msgacc, const float* __restrict__ lacc,
    const u16* __restrict__ WoT, const float* __restrict__ bo,
    const float* __restrict__ x, const float* __restrict__ gamma,
    const float* __restrict__ beta, float* __restrict__ out)
{
    __shared__ float sums[2][4][OROWS];
    const int m0 = blockIdx.x * OROWS;
    const int t = threadIdx.x;
    const int w = t >> 6, lane = t & 63;
    const int l16 = lane & 15, quad = lane >> 4;

    f32x4 acc[4];
    #pragma unroll
    for (int ct = 0; ct < 4; ++ct) acc[ct] = f32x4{0.f, 0.f, 0.f, 0.f};

    const int ar = min(m0 + l16, NN - 1);    // rows 8..15 feed discarded D rows
    const float* arow = msgacc + (size_t)ar * C;
    const float* lrow = lacc + (size_t)ar * NH;
    #pragma unroll
    for (int kk = 0; kk < 8; ++kk) {
        const float li = 1.f / lrow[kk];
        const float4 a0 = *(const float4*)(arow + kk * 32 + quad * 8);
        const float4 a1 = *(const float4*)(arow + kk * 32 + quad * 8 + 4);
        union { unsigned u[4]; bf16x8 v; } af;
        af.u[0] = pack_trunc(a0.x * li, a0.y * li);
        af.u[1] = pack_trunc(a0.z * li, a0.w * li);
        af.u[2] = pack_trunc(a1.x * li, a1.y * li);
        af.u[3] = pack_trunc(a1.z * li, a1.w * li);
        #pragma unroll
        for (int ct = 0; ct < 4; ++ct) {
            const bf16x8 bfr = *(const bf16x8*)(
                WoT + (size_t)(w * 64 + ct * 16 + l16) * C + kk * 32 + quad * 8);
            acc[ct] = __builtin_amdgcn_mfma_f32_16x16x32_bf16(af.v, bfr, acc[ct], 0, 0, 0);
        }
    }

    float val[4][4];
    if (quad < 2) {
        #pragma unroll
        for (int r = 0; r < 4; ++r) {
            const int row = m0 + quad * 4 + r;
            float sr = 0.f, qr = 0.f;
            #pragma unroll
            for (int ct = 0; ct < 4; ++ct) {
                const int c = w * 64 + ct * 16 + l16;
                const float v = acc[ct][r] + bo[c] + x[(size_t)row * C + c];
                val[ct][r] = v;
                sr += v;
                qr = fmaf(v, v, qr);
            }
            sr += __shfl_xor(sr, 1); sr += __shfl_xor(sr, 2);
            sr += __shfl_xor(sr, 4); sr += __shfl_xor(sr, 8);
            qr += __shfl_xor(qr, 1); qr += __shfl_xor(qr, 2);
            qr += __shfl_xor(qr, 4); qr += __shfl_xor(qr, 8);
            if (l16 == 0) {
                sums[0][w][quad * 4 + r] = sr;
                sums[1][w][quad * 4 + r] = qr;
            }
        }
    }
    __syncthreads();

    if (quad < 2) {
        #pragma unroll
        for (int r = 0; r < 4; ++r) {
            const int ri = quad * 4 + r;
            const int row = m0 + ri;
            const float tot  = sums[0][0][ri] + sums[0][1][ri] + sums[0][2][ri] + sums[0][3][ri];
            const float tot2 = sums[1][0][ri] + sums[1][1][ri] + sums[1][2][ri] + sums[1][3][ri];
            const float mu = tot * (1.f / C);
            const float var = fmaxf(tot2 * (1.f / C) - mu * mu, 0.f);
            const float rstd = rsqrtf(var + LN_EPS);
            #pragma unroll
            for (int ct = 0; ct < 4; ++ct) {
                const int c = w * 64 + ct * 16 + l16;
                out[(size_t)row * C + c] = (val[ct][r] - mu) * rstd * gamma[c] + beta[c];
            }
        }
    }
}

// ---------------------------------------------------------------------------
extern "C" void kernel_launch(void* const* d_in, const int* in_sizes, int n_in,
                              void* d_out, int out_size, void* d_ws, size_t ws_size,
                              hipStream_t stream) {
    const float* x     = (const float*)d_in[0];
    const float* Wq    = (const float*)d_in[1];
    const float* bq    = (const float*)d_in[2];
    const float* Wk    = (const float*)d_in[3];
    const float* bk    = (const float*)d_in[4];
    const float* Wv    = (const float*)d_in[5];
    const float* bv    = (const float*)d_in[6];
    const float* scale = (const float*)d_in[7];
    const float* Wo    = (const float*)d_in[8];
    const float* bo    = (const float*)d_in[9];
    const float* gamma = (const float*)d_in[10];
    const float* beta  = (const float*)d_in[11];
    float* out = (float*)d_out;

    u16* qb     = (u16*)d_ws;                              // 2 MB
    u16* kb     = qb + (size_t)NN * C;                     // 2 MB
    u16* vT     = kb + (size_t)NN * C;                     // 2 MB
    u16* xbuf   = vT + (size_t)NN * C;                     // 2 MB
    u16* WqkvT  = xbuf + (size_t)NN * C;                   // 384 KB
    u16* WoT    = WqkvT + (size_t)3 * C * C;               // 128 KB
    float* msgacc = (float*)(WoT + (size_t)C * C);         // 4 MB
    float* lacc   = msgacc + (size_t)NN * C;               // 128 KB (contiguous)

    hipMemsetAsync(msgacc, 0, ((size_t)NN * C + (size_t)NN * NH) * sizeof(float),
                   stream);

    prep_kernel<<<dim3(8, 8, 8), 256, 0, stream>>>(Wq, Wk, Wv, Wo, x,
                                                   WqkvT, WoT, xbuf);
    qkv_mfma_kernel<<<dim3(NN / 64, 12), 256, 0, stream>>>(
        xbuf, WqkvT, bq, bk, bv, scale, qb, kb, vT);
    attn_mfma_kernel<<<dim3(NN / TQ, NH, NZ), 256, 0, stream>>>(
        qb, kb, vT, msgacc, lacc);
    out_ln_mfma_kernel<<<NN / OROWS, 256, 0, stream>>>(msgacc, lacc, WoT, bo, x,
                                                       gamma, beta, out);
}